// Round 11
// baseline (207.517 us; speedup 1.0000x reference)
//
#include <hip/hip_runtime.h>
#include <cstdint>

#define N_VIS   8192
#define N_ASSOC 4096
#define N_MOTOR 1024
#define IN_DIM  4096
#define T_STEPS 16

// ---------------- shared core: Sp[sp][j][t] = sum_{i in seg sp} W[j,i] * V[t][i] ----------------
// 256 threads: c = tid&63 (f4 col within chunk), g = tid>>6 (t-group of 4). 4 rows per block.
// CS = split-K factor; partials are summed (ascending sp) in the consumer kernels.
// Fine CS (seg = 2 chunks) => sibling blocks tile each row densely => HBM page locality.
template<int COLS, int CS>
__global__ __launch_bounds__(256, 4) void matvec16_kernel(
        const float* __restrict__ Wg, const float* __restrict__ Vg,
        float* __restrict__ Sp, int nrows) {
    constexpr int F4PR = COLS / 4;           // float4 per row
    constexpr int SEG4 = F4PR / CS;          // float4 per split segment
    constexpr int KIT  = SEG4 / 64;          // chunks of 64 f4 (KIT=2 everywhere here)
    const int c  = threadIdx.x & 63;
    const int g  = threadIdx.x >> 6;
    const int j0 = (blockIdx.x / CS) * 4;
    const int sp = blockIdx.x % CS;
    const float4* W4 = (const float4*)Wg + (size_t)j0 * F4PR + (size_t)sp * SEG4;
    const float4* V4 = (const float4*)Vg + (size_t)(g * 4) * F4PR + (size_t)sp * SEG4;

    float acc[4][4];
#pragma unroll
    for (int r = 0; r < 4; ++r)
#pragma unroll
        for (int q = 0; q < 4; ++q) acc[r][q] = 0.f;

    // issue ALL loads (KIT*8 float4) before the FMA block; KIT=2 -> 16 loads in flight
    float4 w[KIT][4], v[KIT][4];
#pragma unroll
    for (int k = 0; k < KIT; ++k) {
        const int idx = k * 64 + c;
        w[k][0] = W4[idx];
        w[k][1] = W4[F4PR + idx];
        w[k][2] = W4[2 * F4PR + idx];
        w[k][3] = W4[3 * F4PR + idx];
        v[k][0] = V4[idx];
        v[k][1] = V4[F4PR + idx];
        v[k][2] = V4[2 * F4PR + idx];
        v[k][3] = V4[3 * F4PR + idx];
    }
#pragma unroll
    for (int k = 0; k < KIT; ++k)
#pragma unroll
        for (int r = 0; r < 4; ++r)
#pragma unroll
            for (int q = 0; q < 4; ++q) {
                acc[r][q] = fmaf(w[k][r].x, v[k][q].x, acc[r][q]);
                acc[r][q] = fmaf(w[k][r].y, v[k][q].y, acc[r][q]);
                acc[r][q] = fmaf(w[k][r].z, v[k][q].z, acc[r][q]);
                acc[r][q] = fmaf(w[k][r].w, v[k][q].w, acc[r][q]);
            }

#pragma unroll
    for (int r = 0; r < 4; ++r)
#pragma unroll
        for (int q = 0; q < 4; ++q) {
            float a = acc[r][q];
            for (int o = 32; o; o >>= 1) a += __shfl_down(a, o, 64);
            acc[r][q] = a;
        }
    if (c == 0) {
#pragma unroll
        for (int r = 0; r < 4; ++r)
#pragma unroll
            for (int q = 0; q < 4; ++q)
                Sp[((size_t)sp * nrows + j0 + r) * 16 + g * 4 + q] = acc[r][q];
    }
}

// ---------------- visual LIF + spike expansion (one thread per visual row) ----------------
// Sums the CS=8 encoder partials in ascending order, then runs the LIF.
__global__ __launch_bounds__(256) void vlif_kernel(
        const float* __restrict__ S1p, const float* __restrict__ noise,
        const float* __restrict__ b, unsigned* __restrict__ vmask,
        float* __restrict__ V) {
    const int i = blockIdx.x * 256 + threadIdx.x;
    float a[T_STEPS];
#pragma unroll
    for (int t = 0; t < T_STEPS; ++t) a[t] = S1p[(size_t)i * 16 + t];
#pragma unroll 1
    for (int s = 1; s < 8; ++s)
#pragma unroll
        for (int t = 0; t < T_STEPS; ++t)
            a[t] += S1p[((size_t)s * N_VIS + i) * 16 + t];
    const float bb = b[i];
    float v = 0.f;
    unsigned msk = 0;
#pragma unroll
    for (int t = 0; t < T_STEPS; ++t) {
        float logit = a[t] + bb;
        float rate = 1.0f / (1.0f + expf(-logit));
        float u = noise[t * N_VIS + i];
        float ins = (u < rate * 0.3f) ? 1.0f : 0.0f;
        v = v * 0.95f + ins;
        if (v > 1.0f) { msk |= (1u << t); v = 0.f; }
    }
    vmask[i] = msk;
#pragma unroll
    for (int t = 0; t < T_STEPS; ++t)
        V[t * N_VIS + i] = (float)((msk >> t) & 1u);
}

// ---------------- K table: K[t][r] = sum_{s=r..t-1} g_s * d_s*0.1*0.01*C[s][r] ----------------
__global__ void ktab_kernel(const float* __restrict__ dop, float* __restrict__ K) {
    __shared__ float C[256];
    __shared__ float sd[16];
    __shared__ unsigned sg[16];
    const int p = threadIdx.x;
    if (p < 16) {
        float d = dop[p];
        sd[p] = d;
        sg[p] = (fabsf(d) > 0.1f) ? 1u : 0u;
    }
    __syncthreads();
    {
        const int s = p >> 4, r = p & 15;
        float c = 0.f;
        if (s >= r) {
            c = 1.f;
            for (int u = r; u < s; ++u) {
                if (sg[u]) c *= 0.5f;
                c *= 0.998f;
            }
        }
        C[p] = c;
    }
    __syncthreads();
    {
        const int t = p >> 4, r = p & 15;
        float kk = 0.f;
        for (int s = r; s < t; ++s)
            if (sg[s]) kk += ((sd[s] * 0.1f) * 0.01f) * C[s * 16 + r];
        K[p] = kk;
    }
}

// ---------------- OVL[r][t] = popcount over mask words of bit_r & bit_t ----------------
__global__ void ovl_kernel(const unsigned* __restrict__ mask, int words_per_block,
                           int* __restrict__ ovl) {
    const int p = threadIdx.x;
    const int r = p >> 4, t = p & 15;
    const unsigned* w = mask + blockIdx.x * words_per_block;
    int c = 0;
    for (int i = 0; i < words_per_block; ++i)
        c += (int)((w[i] >> r) & (w[i] >> t) & 1u);
    atomicAdd(&ovl[p], c);
}

// ---------------- tiny sequential recursion; sums cs partials; optional spike expansion ----
__global__ __launch_bounds__(64) void rec_kernel(
        const float* __restrict__ base, const int* __restrict__ ovl,
        const float* __restrict__ K, unsigned* __restrict__ mask_out,
        float* __restrict__ outp, int out_stride,
        float* __restrict__ outV, int n_rows, int cs) {
    __shared__ float KO[256];
    const int tid = threadIdx.x;
    for (int p = tid; p < 256; p += 64) {
        const int t = p >> 4, r = p & 15;
        KO[p] = K[p] * (float)ovl[r * 16 + t];
    }
    __syncthreads();

    const int j = blockIdx.x * 64 + tid;
    float br[T_STEPS];
#pragma unroll
    for (int t = 0; t < T_STEPS; ++t) br[t] = base[(size_t)j * 16 + t];
#pragma unroll 1
    for (int s = 1; s < cs; ++s)
#pragma unroll
        for (int t = 0; t < T_STEPS; ++t)
            br[t] += base[((size_t)s * n_rows + j) * 16 + t];

    float vmem = 0.f;
    unsigned am = 0;
#pragma unroll
    for (int t = 0; t < T_STEPS; ++t) {
        float I = br[t];
        for (int r = 0; r < t; ++r)
            if ((am >> r) & 1u) I += KO[t * 16 + r];
        vmem = vmem * 0.95f + I * 0.1f;
        const bool s = vmem > 1.0f;
        if (s) { vmem = 0.f; am |= (1u << t); }
        if (outp) outp[t * out_stride + j] = s ? 1.0f : 0.0f;
    }
    mask_out[j] = am;
    if (outV) {
#pragma unroll
        for (int t = 0; t < T_STEPS; ++t)
            outV[t * n_rows + j] = (float)((am >> t) & 1u);
    }
}

extern "C" void kernel_launch(void* const* d_in, const int* in_sizes, int n_in,
                              void* d_out, int out_size, void* d_ws, size_t ws_size,
                              hipStream_t stream) {
    const float* x     = (const float*)d_in[0];   // [16, 4096]
    const float* noise = (const float*)d_in[1];   // [16, 8192]
    const float* dop   = (const float*)d_in[2];   // [16]
    const float* W_enc = (const float*)d_in[3];   // [8192, 4096]
    const float* b_enc = (const float*)d_in[4];   // [8192]
    const float* W_va  = (const float*)d_in[5];   // [4096, 8192]
    const float* W_am  = (const float*)d_in[6];   // [1024, 4096]
    float* out = (float*)d_out;                   // [16, 1024] f32
    (void)in_sizes; (void)n_in; (void)out_size; (void)ws_size;

    char* ws = (char*)d_ws;
    size_t off = 0;
    unsigned* vmask = (unsigned*)(ws + off); off += N_VIS * 4;
    unsigned* amask = (unsigned*)(ws + off); off += N_ASSOC * 4;
    unsigned* mmask = (unsigned*)(ws + off); off += N_MOTOR * 4;
    float*    K     = (float*)(ws + off);    off += 256 * 4;
    int*      ovl_v = (int*)(ws + off);      off += 256 * 4;
    int*      ovl_a = (int*)(ws + off);      off += 256 * 4;
    float*    S1    = (float*)(ws + off);    off += (size_t)8  * N_VIS   * 16 * 4;
    float*    S2    = (float*)(ws + off);    off += (size_t)16 * N_ASSOC * 16 * 4;
    float*    S3    = (float*)(ws + off);    off += (size_t)8  * N_MOTOR * 16 * 4;
    float*    Vv    = (float*)(ws + off);    off += (size_t)T_STEPS * N_VIS * 4;
    float*    Va    = (float*)(ws + off);    off += (size_t)T_STEPS * N_ASSOC * 4;

    hipMemsetAsync(ovl_v, 0, 2 * 256 * 4, stream);   // ovl_v and ovl_a are adjacent

    ktab_kernel<<<1, 256, 0, stream>>>(dop, K);
    // visual encoder: S1 = W_enc @ x^T  (x is the dense V matrix), CS=8
    matvec16_kernel<IN_DIM, 8><<<(N_VIS / 4) * 8, 256, 0, stream>>>(W_enc, x, S1, N_VIS);
    vlif_kernel<<<N_VIS / 256, 256, 0, stream>>>(S1, noise, b_enc, vmask, Vv);
    ovl_kernel<<<32, 256, 0, stream>>>(vmask, N_VIS / 32, ovl_v);
    // assoc layer, CS=16
    matvec16_kernel<N_VIS, 16><<<(N_ASSOC / 4) * 16, 256, 0, stream>>>(W_va, Vv, S2, N_ASSOC);
    rec_kernel<<<N_ASSOC / 64, 64, 0, stream>>>(S2, ovl_v, K, amask, nullptr, 0, Va, N_ASSOC, 16);
    ovl_kernel<<<16, 256, 0, stream>>>(amask, N_ASSOC / 16, ovl_a);
    // motor layer, CS=8
    matvec16_kernel<N_ASSOC, 8><<<(N_MOTOR / 4) * 8, 256, 0, stream>>>(W_am, Va, S3, N_MOTOR);
    rec_kernel<<<N_MOTOR / 64, 64, 0, stream>>>(S3, ovl_a, K, mmask, out, N_MOTOR, nullptr, 0, 8);
}

// Round 12
// 163.854 us; speedup vs baseline: 1.2665x; 1.2665x over previous
//
#include <hip/hip_runtime.h>
#include <cstdint>

#define N_VIS   8192
#define N_ASSOC 4096
#define N_MOTOR 1024
#define IN_DIM  4096
#define T_STEPS 16

// ---------------- row-wave matvec: S[j][t] = sum_i W[j,i] * V[t][i] ----------------
// One row per WAVE (contiguous 32KB W stream per wave); 8 waves/block share a
// double-buffered LDS tile of V[16][64 f4]. V amplification: 512 KB per block total.
template<int COLS>
__global__ __launch_bounds__(512, 4) void mv_rowwave_kernel(
        const float* __restrict__ Wg, const float* __restrict__ Vg,
        float* __restrict__ S) {
    constexpr int F4PR = COLS / 4;            // float4 per row
    constexpr int NIT  = F4PR / 64;           // iterations of 64 f4
    __shared__ float4 vs[2][16 * 64];         // 2 x 16 KB
    const int tid  = threadIdx.x;
    const int lane = tid & 63, wv = tid >> 6; // 8 waves
    const int row  = blockIdx.x * 8 + wv;
    const float4* W4 = (const float4*)Wg + (size_t)row * F4PR;
    const float4* V4 = (const float4*)Vg;     // [16][F4PR]

    float acc[T_STEPS];
#pragma unroll
    for (int t = 0; t < T_STEPS; ++t) acc[t] = 0.f;

    // stage iter 0 (wave w stages V rows w and w+8: contiguous 1 KB per row)
    {
        int f = tid;
#pragma unroll
        for (int p = 0; p < 2; ++p, f += 512) {
            int t = f >> 6, c = f & 63;
            vs[0][f] = V4[(size_t)t * F4PR + c];
        }
    }
    float4 w = W4[lane];
    __syncthreads();

    int buf = 0;
#pragma unroll 1
    for (int it = 0; it < NIT; ++it) {
        float4 wn = w;
        if (it + 1 < NIT) {
            wn = W4[(it + 1) * 64 + lane];            // prefetch next W f4 (contiguous)
            int f = tid;
#pragma unroll
            for (int p = 0; p < 2; ++p, f += 512) {   // stage next V tile into other buffer
                int t = f >> 6, c = f & 63;
                vs[buf ^ 1][f] = V4[(size_t)t * F4PR + (it + 1) * 64 + c];
            }
        }
#pragma unroll
        for (int t = 0; t < T_STEPS; ++t) {           // consume current buffer
            float4 v = vs[buf][t * 64 + lane];
            acc[t] = fmaf(w.x, v.x, acc[t]);
            acc[t] = fmaf(w.y, v.y, acc[t]);
            acc[t] = fmaf(w.z, v.z, acc[t]);
            acc[t] = fmaf(w.w, v.w, acc[t]);
        }
        __syncthreads();                              // next stage may overwrite after this
        w = wn; buf ^= 1;
    }

#pragma unroll
    for (int t = 0; t < T_STEPS; ++t) {
        float a = acc[t];
        for (int o = 32; o; o >>= 1) a += __shfl_down(a, o, 64);
        acc[t] = a;
    }
    if (lane == 0) {
        float4* So = (float4*)(S + (size_t)row * 16);
#pragma unroll
        for (int q = 0; q < 4; ++q)
            So[q] = make_float4(acc[q*4], acc[q*4+1], acc[q*4+2], acc[q*4+3]);
    }
}

// ---------------- visual LIF + spike expansion (one thread per visual row) ----------------
__global__ __launch_bounds__(256) void vlif_kernel(
        const float* __restrict__ S1, const float* __restrict__ noise,
        const float* __restrict__ b, unsigned* __restrict__ vmask,
        float* __restrict__ V) {
    const int i = blockIdx.x * 256 + threadIdx.x;
    float a[T_STEPS];
#pragma unroll
    for (int t = 0; t < T_STEPS; ++t) a[t] = S1[(size_t)i * 16 + t];
    const float bb = b[i];
    float v = 0.f;
    unsigned msk = 0;
#pragma unroll
    for (int t = 0; t < T_STEPS; ++t) {
        float logit = a[t] + bb;
        float rate = 1.0f / (1.0f + expf(-logit));
        float u = noise[t * N_VIS + i];
        float ins = (u < rate * 0.3f) ? 1.0f : 0.0f;
        v = v * 0.95f + ins;
        if (v > 1.0f) { msk |= (1u << t); v = 0.f; }
    }
    vmask[i] = msk;
#pragma unroll
    for (int t = 0; t < T_STEPS; ++t)
        V[t * N_VIS + i] = (float)((msk >> t) & 1u);
}

// ---------------- K table ----------------
__global__ void ktab_kernel(const float* __restrict__ dop, float* __restrict__ K) {
    __shared__ float C[256];
    __shared__ float sd[16];
    __shared__ unsigned sg[16];
    const int p = threadIdx.x;
    if (p < 16) {
        float d = dop[p];
        sd[p] = d;
        sg[p] = (fabsf(d) > 0.1f) ? 1u : 0u;
    }
    __syncthreads();
    {
        const int s = p >> 4, r = p & 15;
        float c = 0.f;
        if (s >= r) {
            c = 1.f;
            for (int u = r; u < s; ++u) {
                if (sg[u]) c *= 0.5f;
                c *= 0.998f;
            }
        }
        C[p] = c;
    }
    __syncthreads();
    {
        const int t = p >> 4, r = p & 15;
        float kk = 0.f;
        for (int s = r; s < t; ++s)
            if (sg[s]) kk += ((sd[s] * 0.1f) * 0.01f) * C[s * 16 + r];
        K[p] = kk;
    }
}

// ---------------- OVL[r][t] = popcount over mask words of bit_r & bit_t ----------------
__global__ void ovl_kernel(const unsigned* __restrict__ mask, int words_per_block,
                           int* __restrict__ ovl) {
    const int p = threadIdx.x;
    const int r = p >> 4, t = p & 15;
    const unsigned* w = mask + blockIdx.x * words_per_block;
    int c = 0;
    for (int i = 0; i < words_per_block; ++i)
        c += (int)((w[i] >> r) & (w[i] >> t) & 1u);
    atomicAdd(&ovl[p], c);
}

// ---------------- tiny sequential recursion; optional spike expansion ----------------
__global__ __launch_bounds__(64) void rec_kernel(
        const float* __restrict__ base, const int* __restrict__ ovl,
        const float* __restrict__ K, unsigned* __restrict__ mask_out,
        float* __restrict__ outp, int out_stride,
        float* __restrict__ outV, int n_rows) {
    __shared__ float KO[256];
    const int tid = threadIdx.x;
    for (int p = tid; p < 256; p += 64) {
        const int t = p >> 4, r = p & 15;
        KO[p] = K[p] * (float)ovl[r * 16 + t];
    }
    __syncthreads();

    const int j = blockIdx.x * 64 + tid;
    float br[T_STEPS];
#pragma unroll
    for (int t = 0; t < T_STEPS; ++t) br[t] = base[(size_t)j * 16 + t];

    float vmem = 0.f;
    unsigned am = 0;
#pragma unroll
    for (int t = 0; t < T_STEPS; ++t) {
        float I = br[t];
        for (int r = 0; r < t; ++r)
            if ((am >> r) & 1u) I += KO[t * 16 + r];
        vmem = vmem * 0.95f + I * 0.1f;
        const bool s = vmem > 1.0f;
        if (s) { vmem = 0.f; am |= (1u << t); }
        if (outp) outp[t * out_stride + j] = s ? 1.0f : 0.0f;
    }
    mask_out[j] = am;
    if (outV) {
#pragma unroll
        for (int t = 0; t < T_STEPS; ++t)
            outV[t * n_rows + j] = (float)((am >> t) & 1u);
    }
}

extern "C" void kernel_launch(void* const* d_in, const int* in_sizes, int n_in,
                              void* d_out, int out_size, void* d_ws, size_t ws_size,
                              hipStream_t stream) {
    const float* x     = (const float*)d_in[0];   // [16, 4096]
    const float* noise = (const float*)d_in[1];   // [16, 8192]
    const float* dop   = (const float*)d_in[2];   // [16]
    const float* W_enc = (const float*)d_in[3];   // [8192, 4096]
    const float* b_enc = (const float*)d_in[4];   // [8192]
    const float* W_va  = (const float*)d_in[5];   // [4096, 8192]
    const float* W_am  = (const float*)d_in[6];   // [1024, 4096]
    float* out = (float*)d_out;                   // [16, 1024] f32
    (void)in_sizes; (void)n_in; (void)out_size; (void)ws_size;

    char* ws = (char*)d_ws;
    size_t off = 0;
    unsigned* vmask = (unsigned*)(ws + off); off += N_VIS * 4;
    unsigned* amask = (unsigned*)(ws + off); off += N_ASSOC * 4;
    unsigned* mmask = (unsigned*)(ws + off); off += N_MOTOR * 4;
    float*    K     = (float*)(ws + off);    off += 256 * 4;
    int*      ovl_v = (int*)(ws + off);      off += 256 * 4;
    int*      ovl_a = (int*)(ws + off);      off += 256 * 4;
    float*    S1    = (float*)(ws + off);    off += (size_t)N_VIS   * 16 * 4;
    float*    S2    = (float*)(ws + off);    off += (size_t)N_ASSOC * 16 * 4;
    float*    S3    = (float*)(ws + off);    off += (size_t)N_MOTOR * 16 * 4;
    float*    Vv    = (float*)(ws + off);    off += (size_t)T_STEPS * N_VIS * 4;
    float*    Va    = (float*)(ws + off);    off += (size_t)T_STEPS * N_ASSOC * 4;

    hipMemsetAsync(ovl_v, 0, 2 * 256 * 4, stream);   // ovl_v and ovl_a are adjacent

    ktab_kernel<<<1, 256, 0, stream>>>(dop, K);
    // visual encoder: S1 = W_enc @ x^T (x is the dense V operand)
    mv_rowwave_kernel<IN_DIM><<<N_VIS / 8, 512, 0, stream>>>(W_enc, x, S1);
    vlif_kernel<<<N_VIS / 256, 256, 0, stream>>>(S1, noise, b_enc, vmask, Vv);
    ovl_kernel<<<32, 256, 0, stream>>>(vmask, N_VIS / 32, ovl_v);
    // assoc layer
    mv_rowwave_kernel<N_VIS><<<N_ASSOC / 8, 512, 0, stream>>>(W_va, Vv, S2);
    rec_kernel<<<N_ASSOC / 64, 64, 0, stream>>>(S2, ovl_v, K, amask, nullptr, 0, Va, N_ASSOC);
    ovl_kernel<<<16, 256, 0, stream>>>(amask, N_ASSOC / 16, ovl_a);
    // motor layer
    mv_rowwave_kernel<N_ASSOC><<<N_MOTOR / 8, 512, 0, stream>>>(W_am, Va, S3);
    rec_kernel<<<N_MOTOR / 64, 64, 0, stream>>>(S3, ovl_a, K, mmask, out, N_MOTOR, nullptr, 0);
}

// Round 13
// 145.280 us; speedup vs baseline: 1.4284x; 1.1278x over previous
//
#include <hip/hip_runtime.h>
#include <cstdint>

#define N_VIS   8192
#define N_ASSOC 4096
#define N_MOTOR 1024
#define IN_DIM  4096
#define T_STEPS 16

// ---------------- row-wave matvec: Sp[sp][j][t] = sum_{i in seg} W[j,i] * V[t][i] ----------------
// TWO rows per WAVE (each V f4 LDS read feeds 8 FMAs); 8 waves/block = 16 rows/block.
// Double-buffered LDS tile of V[16][64 f4]; one barrier per 1KB-of-W iteration.
// CS = split-K; partials summed ascending-sp in consumers.
template<int COLS, int CS>
__global__ __launch_bounds__(512, 4) void mv_rowwave_kernel(
        const float* __restrict__ Wg, const float* __restrict__ Vg,
        float* __restrict__ Sp, int nrows) {
    constexpr int F4PR = COLS / 4;            // float4 per full row
    constexpr int SEG4 = F4PR / CS;           // float4 per split segment
    constexpr int NIT  = SEG4 / 64;           // iterations of 64 f4
    __shared__ float4 vs[2][16 * 64];         // 2 x 16 KB
    const int tid  = threadIdx.x;
    const int lane = tid & 63, wv = tid >> 6; // 8 waves
    const int rb   = blockIdx.x / CS;
    const int sp   = blockIdx.x % CS;
    const int j0   = rb * 16 + wv * 2;        // this wave's two rows
    const float4* W4a = (const float4*)Wg + (size_t)j0 * F4PR + (size_t)sp * SEG4;
    const float4* W4b = W4a + F4PR;
    const float4* V4  = (const float4*)Vg + (size_t)sp * SEG4;   // [16][F4PR] + seg offset

    float acc[2][T_STEPS];
#pragma unroll
    for (int t = 0; t < T_STEPS; ++t) { acc[0][t] = 0.f; acc[1][t] = 0.f; }

    {   // stage iter 0
        int f = tid;
#pragma unroll
        for (int p = 0; p < 2; ++p, f += 512) {
            int t = f >> 6, c = f & 63;
            vs[0][f] = V4[(size_t)t * F4PR + c];
        }
    }
    float4 wa = W4a[lane], wb = W4b[lane];
    __syncthreads();

    int buf = 0;
#pragma unroll 1
    for (int it = 0; it < NIT; ++it) {
        float4 wan = wa, wbn = wb;
        if (it + 1 < NIT) {
            wan = W4a[(it + 1) * 64 + lane];          // contiguous W prefetch (both rows)
            wbn = W4b[(it + 1) * 64 + lane];
            int f = tid;
#pragma unroll
            for (int p = 0; p < 2; ++p, f += 512) {   // stage next V tile
                int t = f >> 6, c = f & 63;
                vs[buf ^ 1][f] = V4[(size_t)t * F4PR + (it + 1) * 64 + c];
            }
        }
#pragma unroll
        for (int t = 0; t < T_STEPS; ++t) {
            float4 v = vs[buf][t * 64 + lane];
            acc[0][t] = fmaf(wa.x, v.x, acc[0][t]);
            acc[0][t] = fmaf(wa.y, v.y, acc[0][t]);
            acc[0][t] = fmaf(wa.z, v.z, acc[0][t]);
            acc[0][t] = fmaf(wa.w, v.w, acc[0][t]);
            acc[1][t] = fmaf(wb.x, v.x, acc[1][t]);
            acc[1][t] = fmaf(wb.y, v.y, acc[1][t]);
            acc[1][t] = fmaf(wb.z, v.z, acc[1][t]);
            acc[1][t] = fmaf(wb.w, v.w, acc[1][t]);
        }
        __syncthreads();
        wa = wan; wb = wbn; buf ^= 1;
    }

#pragma unroll
    for (int t = 0; t < T_STEPS; ++t) {
        float a0 = acc[0][t], a1 = acc[1][t];
        for (int o = 32; o; o >>= 1) {
            a0 += __shfl_down(a0, o, 64);
            a1 += __shfl_down(a1, o, 64);
        }
        acc[0][t] = a0; acc[1][t] = a1;
    }
    if (lane == 0) {
#pragma unroll
        for (int r = 0; r < 2; ++r) {
            float4* So = (float4*)(Sp + ((size_t)sp * nrows + j0 + r) * 16);
#pragma unroll
            for (int q = 0; q < 4; ++q)
                So[q] = make_float4(acc[r][q*4], acc[r][q*4+1], acc[r][q*4+2], acc[r][q*4+3]);
        }
    }
}

// ---------------- visual LIF + spike expansion (one thread per visual row) ----------------
__global__ __launch_bounds__(256) void vlif_kernel(
        const float* __restrict__ S1, const float* __restrict__ noise,
        const float* __restrict__ b, unsigned* __restrict__ vmask,
        float* __restrict__ V) {
    const int i = blockIdx.x * 256 + threadIdx.x;
    float a[T_STEPS];
#pragma unroll
    for (int t = 0; t < T_STEPS; ++t) a[t] = S1[(size_t)i * 16 + t];
    const float bb = b[i];
    float v = 0.f;
    unsigned msk = 0;
#pragma unroll
    for (int t = 0; t < T_STEPS; ++t) {
        float logit = a[t] + bb;
        float rate = 1.0f / (1.0f + expf(-logit));
        float u = noise[t * N_VIS + i];
        float ins = (u < rate * 0.3f) ? 1.0f : 0.0f;
        v = v * 0.95f + ins;
        if (v > 1.0f) { msk |= (1u << t); v = 0.f; }
    }
    vmask[i] = msk;
#pragma unroll
    for (int t = 0; t < T_STEPS; ++t)
        V[t * N_VIS + i] = (float)((msk >> t) & 1u);
}

// ---------------- K table (+ zeroing of the ovl accumulators; drops one dispatch) ----------
__global__ void ktab_kernel(const float* __restrict__ dop, float* __restrict__ K,
                            int* __restrict__ ovl_z) {
    __shared__ float C[256];
    __shared__ float sd[16];
    __shared__ unsigned sg[16];
    const int p = threadIdx.x;
    ovl_z[p] = 0; ovl_z[p + 256] = 0;
    if (p < 16) {
        float d = dop[p];
        sd[p] = d;
        sg[p] = (fabsf(d) > 0.1f) ? 1u : 0u;
    }
    __syncthreads();
    {
        const int s = p >> 4, r = p & 15;
        float c = 0.f;
        if (s >= r) {
            c = 1.f;
            for (int u = r; u < s; ++u) {
                if (sg[u]) c *= 0.5f;
                c *= 0.998f;
            }
        }
        C[p] = c;
    }
    __syncthreads();
    {
        const int t = p >> 4, r = p & 15;
        float kk = 0.f;
        for (int s = r; s < t; ++s)
            if (sg[s]) kk += ((sd[s] * 0.1f) * 0.01f) * C[s * 16 + r];
        K[p] = kk;
    }
}

// ---------------- OVL[r][t] = popcount over mask words of bit_r & bit_t ----------------
__global__ void ovl_kernel(const unsigned* __restrict__ mask, int words_per_block,
                           int* __restrict__ ovl) {
    const int p = threadIdx.x;
    const int r = p >> 4, t = p & 15;
    const unsigned* w = mask + blockIdx.x * words_per_block;
    int c = 0;
    for (int i = 0; i < words_per_block; ++i)
        c += (int)((w[i] >> r) & (w[i] >> t) & 1u);
    atomicAdd(&ovl[p], c);
}

// ---------------- tiny sequential recursion; sums cs partials; optional spike expansion ----
__global__ __launch_bounds__(64) void rec_kernel(
        const float* __restrict__ base, const int* __restrict__ ovl,
        const float* __restrict__ K, unsigned* __restrict__ mask_out,
        float* __restrict__ outp, int out_stride,
        float* __restrict__ outV, int n_rows, int cs) {
    __shared__ float KO[256];
    const int tid = threadIdx.x;
    for (int p = tid; p < 256; p += 64) {
        const int t = p >> 4, r = p & 15;
        KO[p] = K[p] * (float)ovl[r * 16 + t];
    }
    __syncthreads();

    const int j = blockIdx.x * 64 + tid;
    float br[T_STEPS];
#pragma unroll
    for (int t = 0; t < T_STEPS; ++t) br[t] = base[(size_t)j * 16 + t];
#pragma unroll 1
    for (int s = 1; s < cs; ++s)
#pragma unroll
        for (int t = 0; t < T_STEPS; ++t)
            br[t] += base[((size_t)s * n_rows + j) * 16 + t];

    float vmem = 0.f;
    unsigned am = 0;
#pragma unroll
    for (int t = 0; t < T_STEPS; ++t) {
        float I = br[t];
        for (int r = 0; r < t; ++r)
            if ((am >> r) & 1u) I += KO[t * 16 + r];
        vmem = vmem * 0.95f + I * 0.1f;
        const bool s = vmem > 1.0f;
        if (s) { vmem = 0.f; am |= (1u << t); }
        if (outp) outp[t * out_stride + j] = s ? 1.0f : 0.0f;
    }
    mask_out[j] = am;
    if (outV) {
#pragma unroll
        for (int t = 0; t < T_STEPS; ++t)
            outV[t * n_rows + j] = (float)((am >> t) & 1u);
    }
}

extern "C" void kernel_launch(void* const* d_in, const int* in_sizes, int n_in,
                              void* d_out, int out_size, void* d_ws, size_t ws_size,
                              hipStream_t stream) {
    const float* x     = (const float*)d_in[0];   // [16, 4096]
    const float* noise = (const float*)d_in[1];   // [16, 8192]
    const float* dop   = (const float*)d_in[2];   // [16]
    const float* W_enc = (const float*)d_in[3];   // [8192, 4096]
    const float* b_enc = (const float*)d_in[4];   // [8192]
    const float* W_va  = (const float*)d_in[5];   // [4096, 8192]
    const float* W_am  = (const float*)d_in[6];   // [1024, 4096]
    float* out = (float*)d_out;                   // [16, 1024] f32
    (void)in_sizes; (void)n_in; (void)out_size; (void)ws_size;

    char* ws = (char*)d_ws;
    size_t off = 0;
    unsigned* vmask = (unsigned*)(ws + off); off += N_VIS * 4;
    unsigned* amask = (unsigned*)(ws + off); off += N_ASSOC * 4;
    unsigned* mmask = (unsigned*)(ws + off); off += N_MOTOR * 4;
    float*    K     = (float*)(ws + off);    off += 256 * 4;
    int*      ovl_v = (int*)(ws + off);      off += 256 * 4;
    int*      ovl_a = (int*)(ws + off);      off += 256 * 4;
    float*    S1    = (float*)(ws + off);    off += (size_t)N_VIS * 16 * 4;
    float*    S2    = (float*)(ws + off);    off += (size_t)2 * N_ASSOC * 16 * 4;
    float*    S3    = (float*)(ws + off);    off += (size_t)4 * N_MOTOR * 16 * 4;
    float*    Vv    = (float*)(ws + off);    off += (size_t)T_STEPS * N_VIS * 4;
    float*    Va    = (float*)(ws + off);    off += (size_t)T_STEPS * N_ASSOC * 4;

    ktab_kernel<<<1, 256, 0, stream>>>(dop, K, ovl_v);   // also zeroes ovl_v/ovl_a
    // visual encoder: S1 = W_enc @ x^T (x is the dense V operand), no split
    mv_rowwave_kernel<IN_DIM, 1><<<N_VIS / 16, 512, 0, stream>>>(W_enc, x, S1, N_VIS);
    vlif_kernel<<<N_VIS / 256, 256, 0, stream>>>(S1, noise, b_enc, vmask, Vv);
    ovl_kernel<<<32, 256, 0, stream>>>(vmask, N_VIS / 32, ovl_v);
    // assoc layer, split-K 2
    mv_rowwave_kernel<N_VIS, 2><<<(N_ASSOC / 16) * 2, 512, 0, stream>>>(W_va, Vv, S2, N_ASSOC);
    rec_kernel<<<N_ASSOC / 64, 64, 0, stream>>>(S2, ovl_v, K, amask, nullptr, 0, Va, N_ASSOC, 2);
    ovl_kernel<<<16, 256, 0, stream>>>(amask, N_ASSOC / 16, ovl_a);
    // motor layer, split-K 4
    mv_rowwave_kernel<N_ASSOC, 4><<<(N_MOTOR / 16) * 4, 512, 0, stream>>>(W_am, Va, S3, N_MOTOR);
    rec_kernel<<<N_MOTOR / 64, 64, 0, stream>>>(S3, ovl_a, K, mmask, out, N_MOTOR, nullptr, 0, 4);
}